// Round 16
// baseline (207.409 us; speedup 1.0000x reference)
//
#include <hip/hip_runtime.h>
#include <hip/hip_bf16.h>
#include <math.h>

// ---- problem constants ----
#define NNODES   20000
#define NEDGES   320000
#define NGRAPHS  100
#define CC       64        // LATENT
#define FLATDIM  576       // C*(1+3+5)
#define POSIN    640       // FLAT + C
#define POSOUT   1600      // NRADII*IRRDIM
#define PAYL     200       // bf16 row: b0'[64] b1'[64] b2'[64] sh[8] -> 400B (25 uint4)
#define EPERM_N  320320    // NEDGES + 5*64 padding

typedef __attribute__((ext_vector_type(8))) short bf16x8;
typedef __attribute__((ext_vector_type(4))) float f32x4;

__device__ __forceinline__ float silu_f(float x){ return x / (1.0f + __expf(-x)); }
__device__ __forceinline__ float sigm_f(float x){ return 1.0f / (1.0f + __expf(-x)); }
__device__ __forceinline__ unsigned pk_bf16(float lo, float hi){
    __hip_bfloat162 t;
    t.x = __float2bfloat16(lo);
    t.y = __float2bfloat16(hi);
    return *reinterpret_cast<unsigned*>(&t);
}
__device__ __forceinline__ unsigned short bf16u(float x){
    __hip_bfloat16 h = __float2bfloat16(x);
    return *reinterpret_cast<unsigned short*>(&h);
}
__device__ __forceinline__ float bf_lo(unsigned u){ return __uint_as_float(u << 16); }
__device__ __forceinline__ float bf_hi(unsigned u){ return __uint_as_float(u & 0xffff0000u); }
__device__ __forceinline__ float bfu(unsigned short u){ return __uint_as_float(((unsigned)u) << 16); }

// ---- prep: w1/w2 n-major bf16; W3L[sp][j]=0.25*w3_j*diag(hs_sp)*lin_j d-major;
//      pos_w bf16; skip_vec; degree; fused species histogram ----
__global__ void prep_kernel(const float* __restrict__ w1, const float* __restrict__ w2,
                            const float* __restrict__ w3,
                            const float* __restrict__ lw0, const float* __restrict__ lw1,
                            const float* __restrict__ lw2,
                            const float* __restrict__ skip_w, const float* __restrict__ node_embed,
                            const float* __restrict__ pos_w,
                            const int* __restrict__ senders,
                            const int* __restrict__ receivers,
                            const int* __restrict__ species,
                            unsigned* __restrict__ w1tn_g,
                            unsigned* __restrict__ w2tn_g, unsigned* __restrict__ w3l_g,
                            float* __restrict__ skip_vec,
                            unsigned* __restrict__ posw_bf,
                            int* __restrict__ degree,
                            int* __restrict__ spcnt)
{
    __shared__ int cnt[5];
    if (threadIdx.x < 5) cnt[threadIdx.x] = 0;
    __syncthreads();

    int tid = blockIdx.x * blockDim.x + threadIdx.x;
    int stride = gridDim.x * blockDim.x;
    for (int i = tid; i < 256; i += stride) {           // w1: 64j x 4 k-pairs (K=8)
        int j = i >> 2, kp = (i & 3) * 2;
        w1tn_g[i] = pk_bf16(w1[kp * 64 + j], w1[(kp + 1) * 64 + j]);
    }
    for (int i = tid; i < 2048; i += stride) {          // w2: 64n x 32 k-pairs
        int n = i >> 5, k = (i & 31) * 2;
        w2tn_g[i] = pk_bf16(w2[k * 64 + n], w2[(k + 1) * 64 + n]);
    }
    // W3L[sp][j][d][k] packed as [sj:15][d:64][kp:32] u32 (pairs over k)
    for (int i = tid; i < 15 * 2048; i += stride) {
        int sj = i >> 11;
        int sp = sj / 3, j = sj - sp * 3;
        int rem = i & 2047;
        int d = rem >> 5, kp = (rem & 31) * 2;
        const float* lw = (j == 0) ? lw0 : (j == 1) ? lw1 : lw2;
        float v0 = 0.f, v1 = 0.f;
        for (int c = 0; c < 64; c++) {
            float t = node_embed[sp * 64 + c] * lw[c * 64 + d];
            v0 += w3[kp * 192 + j * 64 + c] * t;
            v1 += w3[(kp + 1) * 192 + j * 64 + c] * t;
        }
        w3l_g[i] = pk_bf16(v0 * 0.25f, v1 * 0.25f);
    }
    for (int i = tid; i < 5 * 64; i += stride) {        // skip_vec[sp][d]
        int sp = i >> 6, d = i & 63;
        float a = 0.0f;
        for (int c = 0; c < 64; c++)
            a += node_embed[sp * 64 + c] * skip_w[(sp * 64 + c) * 64 + d];
        skip_vec[i] = a;
    }
    for (int i = tid; i < 640 * 800; i += stride) {     // pos_w: [640][800 o-pairs]
        int k = i / 800, o = (i - k * 800) * 2;
        posw_bf[i] = pk_bf16(pos_w[(size_t)k * 1600 + o], pos_w[(size_t)k * 1600 + o + 1]);
    }
    for (int e = tid; e < NEDGES; e += stride) {
        atomicAdd(&degree[receivers[e]], 1);
        atomicAdd(&cnt[species[senders[e]]], 1);
    }
    __syncthreads();
    if (threadIdx.x < 5 && cnt[threadIdx.x] > 0)
        atomicAdd(&spcnt[threadIdx.x], cnt[threadIdx.x]);
}

// ---- scan: CSR start[] + species bucket starts pstart[6] + graph-first flags ----
__global__ __launch_bounds__(1024) void scan_kernel(const int* __restrict__ degree,
                                                    const int* __restrict__ spcnt,
                                                    const int* __restrict__ n_node,
                                                    int* __restrict__ start,
                                                    int* __restrict__ pstart,
                                                    int* __restrict__ flags)
{
    __shared__ int partial[1024];
    int t = threadIdx.x;

    // parallel graph-first flags (L1-hot n_node re-reads)
    if (t < NGRAPHS) {
        int off = 0;
        for (int g = 0; g < t; g++) off += n_node[g];
        flags[off] = t + 1;
    }

    int base = t * 20;
    int s = 0;
    int loc[20];
    for (int i = 0; i < 20; i++) {
        int idx = base + i;
        int d = (idx < NNODES) ? degree[idx] : 0;
        loc[i] = s;
        s += d;
    }
    partial[t] = s;
    __syncthreads();
    if (t == 0) {
        int run = 0;
        for (int i = 0; i < 1024; i++) { int x = partial[i]; partial[i] = run; run += x; }
        start[NNODES] = run;
        int p = 0;
        for (int sp = 0; sp < 5; sp++) {
            pstart[sp] = p;
            p += ((spcnt[sp] + 63) >> 6) << 6;
        }
        pstart[5] = p;
    }
    __syncthreads();
    int off = partial[t];
    for (int i = 0; i < 20; i++) {
        int idx = base + i;
        if (idx < NNODES) start[idx] = off + loc[i];
    }
}

// ---- bucket: scatter edges into species-contiguous eperm (64-aligned regions) ----
__global__ __launch_bounds__(256) void bucket_kernel(const int* __restrict__ senders,
                                                     const int* __restrict__ species,
                                                     const int* __restrict__ pstart,
                                                     int* __restrict__ grant,
                                                     int* __restrict__ eperm)
{
    __shared__ int cnt[5];
    __shared__ int base[5];
    int t = threadIdx.x;
    if (t < 5) cnt[t] = 0;
    __syncthreads();
    int e = blockIdx.x * 256 + t;
    int sp = species[senders[e]];
    int rank = atomicAdd(&cnt[sp], 1);
    __syncthreads();
    if (t < 5) base[t] = (cnt[t] > 0) ? atomicAdd(&grant[t], cnt[t]) : 0;
    __syncthreads();
    eperm[pstart[sp] + base[sp] + rank] = e;
}

// swizzled LDS byte offset for [row][128B] tiles: XOR row bits into 16B-slot bits (G4)
__device__ __forceinline__ int swz(int row, int kbyte){
    return row * 128 + (kbyte ^ ((row & 7) << 4));
}
__device__ __forceinline__ bf16x8 ld_frag(const unsigned char* base, int row, int kbyte){
    return *reinterpret_cast<const bf16x8*>(base + swz(row, kbyte));
}
__device__ __forceinline__ bf16x8 ld_gfrag(const unsigned* base, int row, int kchunk){
    return *reinterpret_cast<const bf16x8*>(base + row * 32 + kchunk * 4);
}

// ---- edge stage: species-uniform tiles; MFMA stages 1-2 + fused stage-3';
//      ~23KB LDS via two-half out-tile -> ~7 blocks/CU ----
__global__ __launch_bounds__(256, 6) void edge_kernel(
    const float* __restrict__ pos, const int* __restrict__ species,
    const int* __restrict__ senders, const int* __restrict__ receivers,
    const unsigned* __restrict__ w1tn_g,
    const unsigned* __restrict__ w2tn_g, const unsigned* __restrict__ w3l_g,
    const int* __restrict__ start, int* __restrict__ cursor,
    const int* __restrict__ eperm, const int* __restrict__ pstart,
    unsigned* __restrict__ payload)
{
    // all-dummy block? (uniform load + uniform exit, before any barrier)
    if (eperm[blockIdx.x * 64] < 0) return;

    __shared__ __align__(16) unsigned char a2l[8192];        // hid1 then hid2, swizzled
    __shared__ __align__(16) unsigned short otl[32 * 192];   // half out-tile (b-values)
    __shared__ __align__(16) unsigned short shl[64 * 8];     // sh per edge row
    __shared__ __align__(16) unsigned rblp[64 * 4];          // rb bf16-pairs per edge
    __shared__ int slotl[64];

    int tid = threadIdx.x;
    int w = tid >> 6, l = tid & 63;
    int lrow = l & 15;
    int kh = l >> 4;           // k-quarter 0..3
    int lkb = kh * 16;         // byte offset within 64B k-half

    // block-uniform sender species from padded bucket starts
    int b64 = blockIdx.x * 64;
    int spb = 0;
    #pragma unroll
    for (int s = 1; s < 5; s++) if (b64 >= pstart[s]) spb = s;

    // prefetch stage-2 B frags from global (registers; overlaps phase A)
    bf16x8 w2b0[4], w2b1[4];
    #pragma unroll
    for (int nt = 0; nt < 4; nt++) {
        w2b0[nt] = ld_gfrag(w2tn_g, nt * 16 + lrow, kh);
        w2b1[nt] = ld_gfrag(w2tn_g, nt * 16 + lrow, 4 + kh);
    }
    // prefetch stage-3' B frags for this block's species
    bf16x8 w3b0[3], w3b1[3];
    #pragma unroll
    for (int nl = 0; nl < 3; nl++) {
        int ntg = 3 * w + nl;
        int j  = ntg >> 2;
        int dt = ntg & 3;
        const unsigned* bb = w3l_g + (spb * 3 + j) * 2048;
        w3b0[nl] = ld_gfrag(bb, dt * 16 + lrow, kh);
        w3b1[nl] = ld_gfrag(bb, dt * 16 + lrow, 4 + kh);
    }
    // prefetch stage-1 B frag (K=32, k>=8 are implicit zeros; only kh==0 lanes carry data)
    bf16x8 w1b[4];
    #pragma unroll
    for (int nt = 0; nt < 4; nt++) {
        bf16x8 z = {0, 0, 0, 0, 0, 0, 0, 0};
        w1b[nt] = (kh == 0) ? *reinterpret_cast<const bf16x8*>(w1tn_g + (nt * 16 + lrow) * 4) : z;
    }

    // ---- phase A: per-edge geometry + CSR slot (one thread per edge) ----
    if (tid < 64) {
        int e = eperm[b64 + tid];
        if (e >= 0) {
            int snd = senders[e];
            int rcv = receivers[e];
            slotl[tid] = start[rcv] + atomicAdd(&cursor[rcv], 1);

            float dx = pos[rcv * 3 + 0] - pos[snd * 3 + 0];
            float dy = pos[rcv * 3 + 1] - pos[snd * 3 + 1];
            float dz = pos[rcv * 3 + 2] - pos[snd * 3 + 2];
            float r = sqrtf(dx * dx + dy * dy + dz * dz);
            float rinv = 1.0f / (r + 1e-9f);
            float ux = dx * rinv, uy = dy * rinv, uz = dz * rinv;

            const float SQ3 = 1.7320508075688772f;
            const float S15 = 3.872983346207417f;
            const float S5  = 2.2360679774997896f;
            shl[tid * 8 + 0] = bf16u(SQ3 * ux);
            shl[tid * 8 + 1] = bf16u(SQ3 * uy);
            shl[tid * 8 + 2] = bf16u(SQ3 * uz);
            shl[tid * 8 + 3] = bf16u(S15 * ux * uy);
            shl[tid * 8 + 4] = bf16u(S15 * uy * uz);
            shl[tid * 8 + 5] = bf16u(0.5f * S5 * (3.0f * uz * uz - 1.0f));
            shl[tid * 8 + 6] = bf16u(S15 * ux * uz);
            shl[tid * 8 + 7] = bf16u(0.5f * S15 * (ux * ux - uy * uy));

            const float PI = 3.14159265358979323846f;
            float rc = r * 0.2f;
            float env = 0.5f * (__cosf(PI * fminf(rc, 1.0f)) + 1.0f);
            float scale = 0.6324555320336759f * rinv * env;
            float rb[8];
            #pragma unroll
            for (int b = 0; b < 8; b++) rb[b] = scale * __sinf((float)(b + 1) * PI * rc);
            #pragma unroll
            for (int p = 0; p < 4; p++)
                rblp[tid * 4 + p] = pk_bf16(rb[2 * p], rb[2 * p + 1]);
        } else {
            slotl[tid] = NEDGES;   // trash row
            #pragma unroll
            for (int p = 0; p < 4; p++) rblp[tid * 4 + p] = 0;
            #pragma unroll
            for (int b = 0; b < 8; b++) shl[tid * 8 + b] = 0;
        }
    }
    __syncthreads();

    // ---- stage 1 MFMA: hid1 = silu(rb @ w1), M=64 K=8(pad 32) N=64 ----
    {
        bf16x8 z = {0, 0, 0, 0, 0, 0, 0, 0};
        bf16x8 aRB = (kh == 0)
            ? *reinterpret_cast<const bf16x8*>(rblp + (16 * w + lrow) * 4) : z;
        #pragma unroll
        for (int nt = 0; nt < 4; nt++) {
            f32x4 c = {0.f, 0.f, 0.f, 0.f};
            c = __builtin_amdgcn_mfma_f32_16x16x32_bf16(aRB, w1b[nt], c, 0, 0, 0);
            int n = nt * 16 + lrow;
            #pragma unroll
            for (int r = 0; r < 4; r++) {
                int m = 16 * w + kh * 4 + r;
                *reinterpret_cast<unsigned short*>(a2l + swz(m, n * 2)) = bf16u(silu_f(c[r]));
            }
        }
    }
    __syncthreads();

    // ---- stage 2 MFMA: hid2 = silu(hid1 @ w2), M=64 K=64 N=64 ----
    {
        bf16x8 aF0 = ld_frag(a2l, 16 * w + lrow, lkb);
        bf16x8 aF1 = ld_frag(a2l, 16 * w + lrow, 64 + lkb);
        f32x4 acc[4];
        #pragma unroll
        for (int nt = 0; nt < 4; nt++) {
            f32x4 c = {0.f, 0.f, 0.f, 0.f};
            c = __builtin_amdgcn_mfma_f32_16x16x32_bf16(aF0, w2b0[nt], c, 0, 0, 0);
            c = __builtin_amdgcn_mfma_f32_16x16x32_bf16(aF1, w2b1[nt], c, 0, 0, 0);
            acc[nt] = c;
        }
        __syncthreads();   // all reads of a2l complete before overwrite
        #pragma unroll
        for (int nt = 0; nt < 4; nt++) {
            int n = nt * 16 + lrow;
            #pragma unroll
            for (int r = 0; r < 4; r++) {
                int m = 16 * w + kh * 4 + r;
                *reinterpret_cast<unsigned short*>(a2l + swz(m, n * 2)) = bf16u(silu_f(acc[nt][r]));
            }
        }
    }
    __syncthreads();

    // ---- stage 3': payload = hid2 @ W3L[spb]; two m-halves through half-size otl ----
    const uint4* sh4 = reinterpret_cast<const uint4*>(shl);
    uint4* pay4 = reinterpret_cast<uint4*>(payload);
    #pragma unroll
    for (int mhalf = 0; mhalf < 2; mhalf++) {
        #pragma unroll
        for (int mtl = 0; mtl < 2; mtl++) {
            int mt = mhalf * 2 + mtl;
            bf16x8 a30 = ld_frag(a2l, 16 * mt + lrow, lkb);
            bf16x8 a31 = ld_frag(a2l, 16 * mt + lrow, 64 + lkb);
            int mbase = 16 * mtl + kh * 4;          // row within otl half
            #pragma unroll
            for (int nl = 0; nl < 3; nl++) {
                f32x4 c = {0.f, 0.f, 0.f, 0.f};
                c = __builtin_amdgcn_mfma_f32_16x16x32_bf16(a30, w3b0[nl], c, 0, 0, 0);
                c = __builtin_amdgcn_mfma_f32_16x16x32_bf16(a31, w3b1[nl], c, 0, 0, 0);
                int o = (3 * w + nl) * 16 + lrow;
                otl[(mbase + 0) * 192 + o] = bf16u(c[0]);
                otl[(mbase + 1) * 192 + o] = bf16u(c[1]);
                otl[(mbase + 2) * 192 + o] = bf16u(c[2]);
                otl[(mbase + 3) * 192 + o] = bf16u(c[3]);
            }
        }
        __syncthreads();

        // copy this half's 32 rows -> payload at CSR slots (8 threads per row)
        {
            const uint4* ot4 = reinterpret_cast<const uint4*>(otl);
            int row = tid >> 3;              // 0..31
            int grow = mhalf * 32 + row;     // global row in tile
            size_t basep = (size_t)slotl[grow] * 25;
            int baser = row * 24;
            int q0 = tid & 7;
            #pragma unroll
            for (int j = 0; j < 4; j++) {
                int q = q0 + 8 * j;
                if (q < 24) pay4[basep + q] = ot4[baser + q];
                else if (q == 24) pay4[basep + 24] = sh4[grow];
            }
        }
        __syncthreads();   // protect otl before next half overwrites
    }
}

// ---- fused gather + gate + heads: one wave per node ----
__global__ __launch_bounds__(256, 4) void node_kernel(
    const unsigned* __restrict__ payload, const int* __restrict__ start,
    const int* __restrict__ species, const float* __restrict__ skip_vec,
    const float* __restrict__ gate_w, const float* __restrict__ focus_w,
    const float* __restrict__ focus_b, const int* __restrict__ flags,
    const float* __restrict__ species_w, const float* __restrict__ species_b,
    float* __restrict__ out_focus, float* __restrict__ out_species,
    float* __restrict__ focus_emb)
{
    int wave = threadIdx.x >> 6;
    int lane = threadIdx.x & 63;
    int n = blockIdx.x * 4 + wave;

    __shared__ float ss[4][64];

    float a0 = 0, a1x = 0, a1y = 0, a1z = 0;
    float a2a = 0, a2b = 0, a2c = 0, a2d = 0, a2e = 0;
    float c0 = 0, c1x = 0, c1y = 0, c1z = 0;
    float c2a = 0, c2b = 0, c2c = 0, c2d = 0, c2e = 0;
    int s0 = start[n], s1 = start[n + 1];
    int i = s0;
    for (; i + 1 < s1; i += 2) {
        const unsigned short* pA = (const unsigned short*)(payload + (size_t)i * (PAYL / 2));
        const unsigned short* pB = (const unsigned short*)(payload + (size_t)(i + 1) * (PAYL / 2));
        float Ab0 = bfu(pA[lane]);
        float Ab1 = bfu(pA[64 + lane]);
        float Ab2 = bfu(pA[128 + lane]);
        uint4 Asv = *reinterpret_cast<const uint4*>(pA + 192);
        float Bb0 = bfu(pB[lane]);
        float Bb1 = bfu(pB[64 + lane]);
        float Bb2 = bfu(pB[128 + lane]);
        uint4 Bsv = *reinterpret_cast<const uint4*>(pB + 192);
        a0  += Ab0;
        a1x += Ab1 * bf_lo(Asv.x); a1y += Ab1 * bf_hi(Asv.x); a1z += Ab1 * bf_lo(Asv.y);
        a2a += Ab2 * bf_hi(Asv.y); a2b += Ab2 * bf_lo(Asv.z); a2c += Ab2 * bf_hi(Asv.z);
        a2d += Ab2 * bf_lo(Asv.w); a2e += Ab2 * bf_hi(Asv.w);
        c0  += Bb0;
        c1x += Bb1 * bf_lo(Bsv.x); c1y += Bb1 * bf_hi(Bsv.x); c1z += Bb1 * bf_lo(Bsv.y);
        c2a += Bb2 * bf_hi(Bsv.y); c2b += Bb2 * bf_lo(Bsv.z); c2c += Bb2 * bf_hi(Bsv.z);
        c2d += Bb2 * bf_lo(Bsv.w); c2e += Bb2 * bf_hi(Bsv.w);
    }
    if (i < s1) {
        const unsigned short* pA = (const unsigned short*)(payload + (size_t)i * (PAYL / 2));
        float Ab0 = bfu(pA[lane]);
        float Ab1 = bfu(pA[64 + lane]);
        float Ab2 = bfu(pA[128 + lane]);
        uint4 Asv = *reinterpret_cast<const uint4*>(pA + 192);
        a0  += Ab0;
        a1x += Ab1 * bf_lo(Asv.x); a1y += Ab1 * bf_hi(Asv.x); a1z += Ab1 * bf_lo(Asv.y);
        a2a += Ab2 * bf_hi(Asv.y); a2b += Ab2 * bf_lo(Asv.z); a2c += Ab2 * bf_hi(Asv.z);
        a2d += Ab2 * bf_lo(Asv.w); a2e += Ab2 * bf_hi(Asv.w);
    }
    float s  = a0 + c0 + skip_vec[species[n] * 64 + lane];
    float v0 = a1x + c1x, v1 = a1y + c1y, v2 = a1z + c1z;
    float t0 = a2a + c2a, t1 = a2b + c2b, t2 = a2c + c2c, t3 = a2d + c2d, t4 = a2e + c2e;

    ss[wave][lane] = s;
    float g1a = 0.0f, g2a = 0.0f;
    #pragma unroll 4
    for (int c = 0; c < 64; c++) {
        float sc = ss[wave][c];
        g1a += sc * gate_w[c * 128 + lane];
        g2a += sc * gate_w[c * 128 + 64 + lane];
    }
    float g1 = sigm_f(g1a), g2 = sigm_f(g2a);
    float s_out = s * sigm_f(s);
    float vo0 = v0 * g1, vo1 = v1 * g1, vo2 = v2 * g1;
    float to0 = t0 * g2, to1 = t1 * g2, to2 = t2 * g2, to3 = t3 * g2, to4 = t4 * g2;

    float pfo = s_out * focus_w[lane]
              + vo0 * focus_w[64 + lane * 3 + 0]
              + vo1 * focus_w[64 + lane * 3 + 1]
              + vo2 * focus_w[64 + lane * 3 + 2]
              + to0 * focus_w[256 + lane * 5 + 0]
              + to1 * focus_w[256 + lane * 5 + 1]
              + to2 * focus_w[256 + lane * 5 + 2]
              + to3 * focus_w[256 + lane * 5 + 3]
              + to4 * focus_w[256 + lane * 5 + 4];
    #pragma unroll
    for (int off = 32; off > 0; off >>= 1) pfo += __shfl_down(pfo, off);
    if (lane == 0) out_focus[n] = pfo + focus_b[0];

    int fg = flags[n];
    if (fg) {
        float* fe = focus_emb + (size_t)(fg - 1) * FLATDIM;
        fe[lane] = s_out;
        fe[64 + lane * 3 + 0] = vo0;
        fe[64 + lane * 3 + 1] = vo1;
        fe[64 + lane * 3 + 2] = vo2;
        fe[256 + lane * 5 + 0] = to0;
        fe[256 + lane * 5 + 1] = to1;
        fe[256 + lane * 5 + 2] = to2;
        fe[256 + lane * 5 + 3] = to3;
        fe[256 + lane * 5 + 4] = to4;

        #pragma unroll
        for (int j = 0; j < 5; j++) {
            float acc = s_out * species_w[lane * 5 + j]
                      + vo0 * species_w[(64 + lane * 3 + 0) * 5 + j]
                      + vo1 * species_w[(64 + lane * 3 + 1) * 5 + j]
                      + vo2 * species_w[(64 + lane * 3 + 2) * 5 + j]
                      + to0 * species_w[(256 + lane * 5 + 0) * 5 + j]
                      + to1 * species_w[(256 + lane * 5 + 1) * 5 + j]
                      + to2 * species_w[(256 + lane * 5 + 2) * 5 + j]
                      + to3 * species_w[(256 + lane * 5 + 3) * 5 + j]
                      + to4 * species_w[(256 + lane * 5 + 4) * 5 + j];
            #pragma unroll
            for (int off = 32; off > 0; off >>= 1) acc += __shfl_down(acc, off);
            if (lane == 0) out_species[(fg - 1) * 5 + j] = acc + species_b[j];
        }
    }
}

// ---- pos head: grid = 100 graphs x 16 k-splits; plain stores to partial buffer ----
__global__ __launch_bounds__(256) void pos_kernel(
    const float* __restrict__ focus_emb, const int* __restrict__ target_species,
    const float* __restrict__ species_embed,
    const unsigned* __restrict__ posw_bf,
    float* __restrict__ partial)
{
    int g  = blockIdx.x >> 4;
    int ks = blockIdx.x & 15;
    int k0 = ks * 40;
    int tid = threadIdx.x;
    __shared__ float pin[40];

    if (tid < 40) {
        int k = k0 + tid;
        pin[tid] = (k < FLATDIM) ? focus_emb[(size_t)g * FLATDIM + k]
                                 : species_embed[target_species[g] * CC + (k - FLATDIM)];
    }
    __syncthreads();

    if (tid < 200) {
        float a0 = 0, a1 = 0, a2 = 0, a3 = 0, a4 = 0, a5 = 0, a6 = 0, a7 = 0;
        const unsigned* wp = posw_bf + (size_t)k0 * 800 + tid * 4;
        #pragma unroll 4
        for (int kk = 0; kk < 40; kk++) {
            uint4 wv = *reinterpret_cast<const uint4*>(wp + (size_t)kk * 800);
            float p = pin[kk];
            a0 += p * bf_lo(wv.x); a1 += p * bf_hi(wv.x);
            a2 += p * bf_lo(wv.y); a3 += p * bf_hi(wv.y);
            a4 += p * bf_lo(wv.z); a5 += p * bf_hi(wv.z);
            a6 += p * bf_lo(wv.w); a7 += p * bf_hi(wv.w);
        }
        float* op = partial + ((size_t)(g * 16 + ks)) * POSOUT + tid * 8;
        *reinterpret_cast<float4*>(op)     = make_float4(a0, a1, a2, a3);
        *reinterpret_cast<float4*>(op + 4) = make_float4(a4, a5, a6, a7);
    }
}

// ---- pos reduce: out_pos[g][o] = pos_b[o] + sum_ks partial[g][ks][o] ----
__global__ __launch_bounds__(256) void posred_kernel(
    const float* __restrict__ partial, const float* __restrict__ pos_b,
    float* __restrict__ out_pos)
{
    int g    = blockIdx.x >> 1;
    int half = blockIdx.x & 1;
    const float* pg = partial + (size_t)g * 16 * POSOUT;
    for (int o = half * 800 + threadIdx.x; o < half * 800 + 800; o += 256) {
        float a = pos_b[o];
        #pragma unroll
        for (int ks = 0; ks < 16; ks++) a += pg[ks * POSOUT + o];
        out_pos[(size_t)g * POSOUT + o] = a;
    }
}

extern "C" void kernel_launch(void* const* d_in, const int* in_sizes, int n_in,
                              void* d_out, int out_size, void* d_ws, size_t ws_size,
                              hipStream_t stream) {
    const float* positions      = (const float*)d_in[0];
    const int*   species        = (const int*)  d_in[1];
    const int*   senders        = (const int*)  d_in[2];
    const int*   receivers      = (const int*)  d_in[3];
    const int*   n_node         = (const int*)  d_in[4];
    const int*   target_species = (const int*)  d_in[5];
    const float* species_embed  = (const float*)d_in[6];
    const float* node_embed     = (const float*)d_in[7];
    const float* radial_w1      = (const float*)d_in[8];
    const float* radial_w2      = (const float*)d_in[9];
    const float* radial_w3      = (const float*)d_in[10];
    const float* lin_w0         = (const float*)d_in[11];
    const float* lin_w1         = (const float*)d_in[12];
    const float* lin_w2         = (const float*)d_in[13];
    const float* skip_w         = (const float*)d_in[14];
    const float* gate_w         = (const float*)d_in[15];
    const float* focus_w        = (const float*)d_in[16];
    const float* focus_b        = (const float*)d_in[17];
    const float* species_w      = (const float*)d_in[18];
    const float* species_b      = (const float*)d_in[19];
    const float* pos_w          = (const float*)d_in[20];
    const float* pos_b          = (const float*)d_in[21];

    // ws layout:
    //   payload [(320000+4 trash)*100 u32]   (pos partial[100*16*1600 f32] ALIASES
    //       the payload head: payload is dead after node_kernel each launch)
    // | posw_bf [512000 u32]
    // | eperm [320320 int]
    // | degree[20000] cursor[20000] flags[20000] (zeroed together)
    // | spcnt[5] grant[5] pad[6] (zeroed with above)
    // | start[20001] pstart[6]
    // | w1tn_g[256 u32] w2tn_g[2048 u32] w3l_g[30720 u32]
    // | skip_vec[320 f32] | focus_emb[57600 f32]
    unsigned* payload = (unsigned*)d_ws;
    float*    partial = (float*)d_ws;     // alias, used after node_kernel
    unsigned* posw_bf = payload + (size_t)(NEDGES + 4) * (PAYL / 2);
    int* eperm  = (int*)(posw_bf + 640 * 800);
    int* degree = eperm + EPERM_N;
    int* cursor = degree + NNODES;
    int* flags  = cursor + NNODES;
    int* spcnt  = flags + NNODES;
    int* grant  = spcnt + 5;
    int* start  = grant + 5 + 6;
    int* pstart = start + NNODES + 1;
    unsigned* w1tn_g = (unsigned*)(pstart + 6);
    unsigned* w2tn_g = w1tn_g + 256;
    unsigned* w3l_g  = w2tn_g + 2048;
    float* skip_vec  = (float*)(w3l_g + 15 * 2048);
    float* focus_emb = skip_vec + 320;

    float* out       = (float*)d_out;
    float* out_focus = out;
    float* out_spec  = out + NNODES;
    float* out_pos   = out + NNODES + NGRAPHS * 5;

    hipMemsetAsync(eperm, 0xFF, EPERM_N * sizeof(int), stream);
    hipMemsetAsync(degree, 0, (3 * NNODES + 16) * sizeof(int), stream);

    prep_kernel<<<512, 256, 0, stream>>>(radial_w1, radial_w2, radial_w3,
                                         lin_w0, lin_w1, lin_w2,
                                         skip_w, node_embed, pos_w,
                                         senders, receivers, species,
                                         w1tn_g, w2tn_g, w3l_g, skip_vec, posw_bf,
                                         degree, spcnt);
    scan_kernel<<<1, 1024, 0, stream>>>(degree, spcnt, n_node, start, pstart, flags);
    bucket_kernel<<<NEDGES / 256, 256, 0, stream>>>(senders, species, pstart, grant, eperm);

    edge_kernel<<<EPERM_N / 64, 256, 0, stream>>>(
        positions, species, senders, receivers,
        w1tn_g, w2tn_g, w3l_g, start, cursor, eperm, pstart, payload);

    node_kernel<<<NNODES / 4, 256, 0, stream>>>(
        payload, start, species, skip_vec,
        gate_w, focus_w, focus_b, flags,
        species_w, species_b, out_focus, out_spec, focus_emb);

    // payload is dead from here on; its head is reused as the pos partial buffer
    pos_kernel<<<NGRAPHS * 16, 256, 0, stream>>>(
        focus_emb, target_species, species_embed, posw_bf, partial);

    posred_kernel<<<NGRAPHS * 2, 256, 0, stream>>>(partial, pos_b, out_pos);
}

// Round 17
// 190.796 us; speedup vs baseline: 1.0871x; 1.0871x over previous
//
#include <hip/hip_runtime.h>
#include <hip/hip_bf16.h>
#include <math.h>

// ---- problem constants ----
#define NNODES   20000
#define NEDGES   320000
#define NGRAPHS  100
#define CC       64        // LATENT
#define FLATDIM  576       // C*(1+3+5)
#define POSIN    640       // FLAT + C
#define POSOUT   1600      // NRADII*IRRDIM
#define PAYL     200       // bf16 row: b0'[64] b1'[64] b2'[64] sh[8] -> 400B (25 uint4)
#define EPERM_N  320320    // NEDGES + 5*64 padding

typedef __attribute__((ext_vector_type(8))) short bf16x8;
typedef __attribute__((ext_vector_type(4))) float f32x4;

__device__ __forceinline__ float silu_f(float x){ return x / (1.0f + __expf(-x)); }
__device__ __forceinline__ float sigm_f(float x){ return 1.0f / (1.0f + __expf(-x)); }
__device__ __forceinline__ unsigned pk_bf16(float lo, float hi){
    __hip_bfloat162 t;
    t.x = __float2bfloat16(lo);
    t.y = __float2bfloat16(hi);
    return *reinterpret_cast<unsigned*>(&t);
}
__device__ __forceinline__ unsigned short bf16u(float x){
    __hip_bfloat16 h = __float2bfloat16(x);
    return *reinterpret_cast<unsigned short*>(&h);
}
__device__ __forceinline__ float bf_lo(unsigned u){ return __uint_as_float(u << 16); }
__device__ __forceinline__ float bf_hi(unsigned u){ return __uint_as_float(u & 0xffff0000u); }
__device__ __forceinline__ float bfu(unsigned short u){ return __uint_as_float(((unsigned)u) << 16); }

// ---- prep: w1/w2 n-major bf16; W3L[sp][j]=0.25*w3_j*diag(hs_sp)*lin_j d-major;
//      pos_w bf16; skip_vec; degree; fused species histogram ----
__global__ void prep_kernel(const float* __restrict__ w1, const float* __restrict__ w2,
                            const float* __restrict__ w3,
                            const float* __restrict__ lw0, const float* __restrict__ lw1,
                            const float* __restrict__ lw2,
                            const float* __restrict__ skip_w, const float* __restrict__ node_embed,
                            const float* __restrict__ pos_w,
                            const int* __restrict__ senders,
                            const int* __restrict__ receivers,
                            const int* __restrict__ species,
                            unsigned* __restrict__ w1tn_g,
                            unsigned* __restrict__ w2tn_g, unsigned* __restrict__ w3l_g,
                            float* __restrict__ skip_vec,
                            unsigned* __restrict__ posw_bf,
                            int* __restrict__ degree,
                            int* __restrict__ spcnt)
{
    __shared__ int cnt[5];
    if (threadIdx.x < 5) cnt[threadIdx.x] = 0;
    __syncthreads();

    int tid = blockIdx.x * blockDim.x + threadIdx.x;
    int stride = gridDim.x * blockDim.x;
    for (int i = tid; i < 256; i += stride) {           // w1: 64j x 4 k-pairs (K=8)
        int j = i >> 2, kp = (i & 3) * 2;
        w1tn_g[i] = pk_bf16(w1[kp * 64 + j], w1[(kp + 1) * 64 + j]);
    }
    for (int i = tid; i < 2048; i += stride) {          // w2: 64n x 32 k-pairs
        int n = i >> 5, k = (i & 31) * 2;
        w2tn_g[i] = pk_bf16(w2[k * 64 + n], w2[(k + 1) * 64 + n]);
    }
    // W3L[sp][j][d][k] packed as [sj:15][d:64][kp:32] u32 (pairs over k)
    for (int i = tid; i < 15 * 2048; i += stride) {
        int sj = i >> 11;
        int sp = sj / 3, j = sj - sp * 3;
        int rem = i & 2047;
        int d = rem >> 5, kp = (rem & 31) * 2;
        const float* lw = (j == 0) ? lw0 : (j == 1) ? lw1 : lw2;
        float v0 = 0.f, v1 = 0.f;
        for (int c = 0; c < 64; c++) {
            float t = node_embed[sp * 64 + c] * lw[c * 64 + d];
            v0 += w3[kp * 192 + j * 64 + c] * t;
            v1 += w3[(kp + 1) * 192 + j * 64 + c] * t;
        }
        w3l_g[i] = pk_bf16(v0 * 0.25f, v1 * 0.25f);
    }
    for (int i = tid; i < 5 * 64; i += stride) {        // skip_vec[sp][d]
        int sp = i >> 6, d = i & 63;
        float a = 0.0f;
        for (int c = 0; c < 64; c++)
            a += node_embed[sp * 64 + c] * skip_w[(sp * 64 + c) * 64 + d];
        skip_vec[i] = a;
    }
    for (int i = tid; i < 640 * 800; i += stride) {     // pos_w: [640][800 o-pairs]
        int k = i / 800, o = (i - k * 800) * 2;
        posw_bf[i] = pk_bf16(pos_w[(size_t)k * 1600 + o], pos_w[(size_t)k * 1600 + o + 1]);
    }
    for (int e = tid; e < NEDGES; e += stride) {
        atomicAdd(&degree[receivers[e]], 1);
        atomicAdd(&cnt[species[senders[e]]], 1);
    }
    __syncthreads();
    if (threadIdx.x < 5 && cnt[threadIdx.x] > 0)
        atomicAdd(&spcnt[threadIdx.x], cnt[threadIdx.x]);
}

// ---- scan: CSR start[] + species bucket starts pstart[6] + graph-first flags ----
__global__ __launch_bounds__(1024) void scan_kernel(const int* __restrict__ degree,
                                                    const int* __restrict__ spcnt,
                                                    const int* __restrict__ n_node,
                                                    int* __restrict__ start,
                                                    int* __restrict__ pstart,
                                                    int* __restrict__ flags)
{
    __shared__ int partial[1024];
    int t = threadIdx.x;

    // parallel graph-first flags (L1-hot n_node re-reads)
    if (t < NGRAPHS) {
        int off = 0;
        for (int g = 0; g < t; g++) off += n_node[g];
        flags[off] = t + 1;
    }

    int base = t * 20;
    int s = 0;
    int loc[20];
    for (int i = 0; i < 20; i++) {
        int idx = base + i;
        int d = (idx < NNODES) ? degree[idx] : 0;
        loc[i] = s;
        s += d;
    }
    partial[t] = s;
    __syncthreads();
    if (t == 0) {
        int run = 0;
        for (int i = 0; i < 1024; i++) { int x = partial[i]; partial[i] = run; run += x; }
        start[NNODES] = run;
        int p = 0;
        for (int sp = 0; sp < 5; sp++) {
            pstart[sp] = p;
            p += ((spcnt[sp] + 63) >> 6) << 6;
        }
        pstart[5] = p;
    }
    __syncthreads();
    int off = partial[t];
    for (int i = 0; i < 20; i++) {
        int idx = base + i;
        if (idx < NNODES) start[idx] = off + loc[i];
    }
}

// ---- bucket: scatter edges into species-contiguous eperm (64-aligned regions) ----
__global__ __launch_bounds__(256) void bucket_kernel(const int* __restrict__ senders,
                                                     const int* __restrict__ species,
                                                     const int* __restrict__ pstart,
                                                     int* __restrict__ grant,
                                                     int* __restrict__ eperm)
{
    __shared__ int cnt[5];
    __shared__ int base[5];
    int t = threadIdx.x;
    if (t < 5) cnt[t] = 0;
    __syncthreads();
    int e = blockIdx.x * 256 + t;
    int sp = species[senders[e]];
    int rank = atomicAdd(&cnt[sp], 1);
    __syncthreads();
    if (t < 5) base[t] = (cnt[t] > 0) ? atomicAdd(&grant[t], cnt[t]) : 0;
    __syncthreads();
    eperm[pstart[sp] + base[sp] + rank] = e;
}

// swizzled LDS byte offset for [row][128B] tiles: XOR row bits into 16B-slot bits (G4)
__device__ __forceinline__ int swz(int row, int kbyte){
    return row * 128 + (kbyte ^ ((row & 7) << 4));
}
__device__ __forceinline__ bf16x8 ld_frag(const unsigned char* base, int row, int kbyte){
    return *reinterpret_cast<const bf16x8*>(base + swz(row, kbyte));
}
__device__ __forceinline__ bf16x8 ld_gfrag(const unsigned* base, int row, int kchunk){
    return *reinterpret_cast<const bf16x8*>(base + row * 32 + kchunk * 4);
}

// ---- edge stage (R15-proven form): species-uniform tiles; MFMA stages 1-2 +
//      fused stage-3'; full out-tile; R15 copy pattern ----
__global__ __launch_bounds__(256, 4) void edge_kernel(
    const float* __restrict__ pos, const int* __restrict__ species,
    const int* __restrict__ senders, const int* __restrict__ receivers,
    const unsigned* __restrict__ w1tn_g,
    const unsigned* __restrict__ w2tn_g, const unsigned* __restrict__ w3l_g,
    const int* __restrict__ start, int* __restrict__ cursor,
    const int* __restrict__ eperm, const int* __restrict__ pstart,
    unsigned* __restrict__ payload)
{
    // all-dummy block? (uniform load + uniform exit, before any barrier)
    if (eperm[blockIdx.x * 64] < 0) return;

    __shared__ __align__(16) unsigned char a2l[8192];       // hid1 then hid2, swizzled
    __shared__ __align__(16) unsigned short otl[64 * PAYL]; // out tile (payload rows)
    __shared__ __align__(16) unsigned rblp[64 * 4];         // rb bf16-pairs per edge
    __shared__ int slotl[64];

    int tid = threadIdx.x;
    int w = tid >> 6, l = tid & 63;
    int lrow = l & 15;
    int kh = l >> 4;           // k-quarter 0..3
    int lkb = kh * 16;         // byte offset within 64B k-half

    // block-uniform sender species from padded bucket starts
    int b64 = blockIdx.x * 64;
    int spb = 0;
    #pragma unroll
    for (int s = 1; s < 5; s++) if (b64 >= pstart[s]) spb = s;

    // prefetch stage-2 B frags from global (registers; overlaps phase A)
    bf16x8 w2b0[4], w2b1[4];
    #pragma unroll
    for (int nt = 0; nt < 4; nt++) {
        w2b0[nt] = ld_gfrag(w2tn_g, nt * 16 + lrow, kh);
        w2b1[nt] = ld_gfrag(w2tn_g, nt * 16 + lrow, 4 + kh);
    }
    // prefetch stage-3' B frags for this block's species
    bf16x8 w3b0[3], w3b1[3];
    #pragma unroll
    for (int nl = 0; nl < 3; nl++) {
        int ntg = 3 * w + nl;
        int j  = ntg >> 2;
        int dt = ntg & 3;
        const unsigned* bb = w3l_g + (spb * 3 + j) * 2048;
        w3b0[nl] = ld_gfrag(bb, dt * 16 + lrow, kh);
        w3b1[nl] = ld_gfrag(bb, dt * 16 + lrow, 4 + kh);
    }
    // prefetch stage-1 B frag (K=32, k>=8 are implicit zeros; only kh==0 lanes carry data)
    bf16x8 w1b[4];
    #pragma unroll
    for (int nt = 0; nt < 4; nt++) {
        bf16x8 z = {0, 0, 0, 0, 0, 0, 0, 0};
        w1b[nt] = (kh == 0) ? *reinterpret_cast<const bf16x8*>(w1tn_g + (nt * 16 + lrow) * 4) : z;
    }

    // ---- phase A: per-edge geometry + CSR slot (one thread per edge) ----
    if (tid < 64) {
        int e = eperm[b64 + tid];
        if (e >= 0) {
            int snd = senders[e];
            int rcv = receivers[e];
            slotl[tid] = start[rcv] + atomicAdd(&cursor[rcv], 1);

            float dx = pos[rcv * 3 + 0] - pos[snd * 3 + 0];
            float dy = pos[rcv * 3 + 1] - pos[snd * 3 + 1];
            float dz = pos[rcv * 3 + 2] - pos[snd * 3 + 2];
            float r = sqrtf(dx * dx + dy * dy + dz * dz);
            float rinv = 1.0f / (r + 1e-9f);
            float ux = dx * rinv, uy = dy * rinv, uz = dz * rinv;

            const float SQ3 = 1.7320508075688772f;
            const float S15 = 3.872983346207417f;
            const float S5  = 2.2360679774997896f;
            otl[tid * PAYL + 192] = bf16u(SQ3 * ux);
            otl[tid * PAYL + 193] = bf16u(SQ3 * uy);
            otl[tid * PAYL + 194] = bf16u(SQ3 * uz);
            otl[tid * PAYL + 195] = bf16u(S15 * ux * uy);
            otl[tid * PAYL + 196] = bf16u(S15 * uy * uz);
            otl[tid * PAYL + 197] = bf16u(0.5f * S5 * (3.0f * uz * uz - 1.0f));
            otl[tid * PAYL + 198] = bf16u(S15 * ux * uz);
            otl[tid * PAYL + 199] = bf16u(0.5f * S15 * (ux * ux - uy * uy));

            const float PI = 3.14159265358979323846f;
            float rc = r * 0.2f;
            float env = 0.5f * (__cosf(PI * fminf(rc, 1.0f)) + 1.0f);
            float scale = 0.6324555320336759f * rinv * env;
            float rb[8];
            #pragma unroll
            for (int b = 0; b < 8; b++) rb[b] = scale * __sinf((float)(b + 1) * PI * rc);
            #pragma unroll
            for (int p = 0; p < 4; p++)
                rblp[tid * 4 + p] = pk_bf16(rb[2 * p], rb[2 * p + 1]);
        } else {
            slotl[tid] = NEDGES;   // trash row
            #pragma unroll
            for (int p = 0; p < 4; p++) rblp[tid * 4 + p] = 0;
            #pragma unroll
            for (int b = 0; b < 8; b++) otl[tid * PAYL + 192 + b] = 0;
        }
    }
    __syncthreads();

    // ---- stage 1 MFMA: hid1 = silu(rb @ w1), M=64 K=8(pad 32) N=64 ----
    {
        bf16x8 z = {0, 0, 0, 0, 0, 0, 0, 0};
        bf16x8 aRB = (kh == 0)
            ? *reinterpret_cast<const bf16x8*>(rblp + (16 * w + lrow) * 4) : z;
        #pragma unroll
        for (int nt = 0; nt < 4; nt++) {
            f32x4 c = {0.f, 0.f, 0.f, 0.f};
            c = __builtin_amdgcn_mfma_f32_16x16x32_bf16(aRB, w1b[nt], c, 0, 0, 0);
            int n = nt * 16 + lrow;
            #pragma unroll
            for (int r = 0; r < 4; r++) {
                int m = 16 * w + kh * 4 + r;
                *reinterpret_cast<unsigned short*>(a2l + swz(m, n * 2)) = bf16u(silu_f(c[r]));
            }
        }
    }
    __syncthreads();

    // ---- stage 2 MFMA: hid2 = silu(hid1 @ w2), M=64 K=64 N=64 ----
    {
        bf16x8 aF0 = ld_frag(a2l, 16 * w + lrow, lkb);
        bf16x8 aF1 = ld_frag(a2l, 16 * w + lrow, 64 + lkb);
        f32x4 acc[4];
        #pragma unroll
        for (int nt = 0; nt < 4; nt++) {
            f32x4 c = {0.f, 0.f, 0.f, 0.f};
            c = __builtin_amdgcn_mfma_f32_16x16x32_bf16(aF0, w2b0[nt], c, 0, 0, 0);
            c = __builtin_amdgcn_mfma_f32_16x16x32_bf16(aF1, w2b1[nt], c, 0, 0, 0);
            acc[nt] = c;
        }
        __syncthreads();   // all reads of a2l complete before overwrite
        #pragma unroll
        for (int nt = 0; nt < 4; nt++) {
            int n = nt * 16 + lrow;
            #pragma unroll
            for (int r = 0; r < 4; r++) {
                int m = 16 * w + kh * 4 + r;
                *reinterpret_cast<unsigned short*>(a2l + swz(m, n * 2)) = bf16u(silu_f(acc[nt][r]));
            }
        }
    }
    __syncthreads();

    // ---- stage 3': payload = hid2 @ W3L[spb], one species, -> otl ----
    {
        #pragma unroll
        for (int mt = 0; mt < 4; mt++) {
            bf16x8 a30 = ld_frag(a2l, 16 * mt + lrow, lkb);
            bf16x8 a31 = ld_frag(a2l, 16 * mt + lrow, 64 + lkb);
            int mbase = 16 * mt + kh * 4;
            #pragma unroll
            for (int nl = 0; nl < 3; nl++) {
                f32x4 c = {0.f, 0.f, 0.f, 0.f};
                c = __builtin_amdgcn_mfma_f32_16x16x32_bf16(a30, w3b0[nl], c, 0, 0, 0);
                c = __builtin_amdgcn_mfma_f32_16x16x32_bf16(a31, w3b1[nl], c, 0, 0, 0);
                int o = (3 * w + nl) * 16 + lrow;
                otl[(mbase + 0) * PAYL + o] = bf16u(c[0]);
                otl[(mbase + 1) * PAYL + o] = bf16u(c[1]);
                otl[(mbase + 2) * PAYL + o] = bf16u(c[2]);
                otl[(mbase + 3) * PAYL + o] = bf16u(c[3]);
            }
        }
    }
    __syncthreads();

    // ---- coalesced copy: out tile rows -> payload rows at CSR slots ----
    {
        const uint4* ot4 = reinterpret_cast<const uint4*>(otl);
        uint4* pay4 = reinterpret_cast<uint4*>(payload);
        for (int i = tid; i < 64 * 25; i += 256) {
            int row = i / 25, q = i - row * 25;
            pay4[(size_t)slotl[row] * 25 + q] = ot4[row * 25 + q];
        }
    }
}

// ---- fused gather + gate + heads: one wave per node ----
__global__ __launch_bounds__(256, 4) void node_kernel(
    const unsigned* __restrict__ payload, const int* __restrict__ start,
    const int* __restrict__ species, const float* __restrict__ skip_vec,
    const float* __restrict__ gate_w, const float* __restrict__ focus_w,
    const float* __restrict__ focus_b, const int* __restrict__ flags,
    const float* __restrict__ species_w, const float* __restrict__ species_b,
    float* __restrict__ out_focus, float* __restrict__ out_species,
    float* __restrict__ focus_emb)
{
    int wave = threadIdx.x >> 6;
    int lane = threadIdx.x & 63;
    int n = blockIdx.x * 4 + wave;

    __shared__ float ss[4][64];

    float a0 = 0, a1x = 0, a1y = 0, a1z = 0;
    float a2a = 0, a2b = 0, a2c = 0, a2d = 0, a2e = 0;
    float c0 = 0, c1x = 0, c1y = 0, c1z = 0;
    float c2a = 0, c2b = 0, c2c = 0, c2d = 0, c2e = 0;
    int s0 = start[n], s1 = start[n + 1];
    int i = s0;
    for (; i + 1 < s1; i += 2) {
        const unsigned short* pA = (const unsigned short*)(payload + (size_t)i * (PAYL / 2));
        const unsigned short* pB = (const unsigned short*)(payload + (size_t)(i + 1) * (PAYL / 2));
        float Ab0 = bfu(pA[lane]);
        float Ab1 = bfu(pA[64 + lane]);
        float Ab2 = bfu(pA[128 + lane]);
        uint4 Asv = *reinterpret_cast<const uint4*>(pA + 192);
        float Bb0 = bfu(pB[lane]);
        float Bb1 = bfu(pB[64 + lane]);
        float Bb2 = bfu(pB[128 + lane]);
        uint4 Bsv = *reinterpret_cast<const uint4*>(pB + 192);
        a0  += Ab0;
        a1x += Ab1 * bf_lo(Asv.x); a1y += Ab1 * bf_hi(Asv.x); a1z += Ab1 * bf_lo(Asv.y);
        a2a += Ab2 * bf_hi(Asv.y); a2b += Ab2 * bf_lo(Asv.z); a2c += Ab2 * bf_hi(Asv.z);
        a2d += Ab2 * bf_lo(Asv.w); a2e += Ab2 * bf_hi(Asv.w);
        c0  += Bb0;
        c1x += Bb1 * bf_lo(Bsv.x); c1y += Bb1 * bf_hi(Bsv.x); c1z += Bb1 * bf_lo(Bsv.y);
        c2a += Bb2 * bf_hi(Bsv.y); c2b += Bb2 * bf_lo(Bsv.z); c2c += Bb2 * bf_hi(Bsv.z);
        c2d += Bb2 * bf_lo(Bsv.w); c2e += Bb2 * bf_hi(Bsv.w);
    }
    if (i < s1) {
        const unsigned short* pA = (const unsigned short*)(payload + (size_t)i * (PAYL / 2));
        float Ab0 = bfu(pA[lane]);
        float Ab1 = bfu(pA[64 + lane]);
        float Ab2 = bfu(pA[128 + lane]);
        uint4 Asv = *reinterpret_cast<const uint4*>(pA + 192);
        a0  += Ab0;
        a1x += Ab1 * bf_lo(Asv.x); a1y += Ab1 * bf_hi(Asv.x); a1z += Ab1 * bf_lo(Asv.y);
        a2a += Ab2 * bf_hi(Asv.y); a2b += Ab2 * bf_lo(Asv.z); a2c += Ab2 * bf_hi(Asv.z);
        a2d += Ab2 * bf_lo(Asv.w); a2e += Ab2 * bf_hi(Asv.w);
    }
    float s  = a0 + c0 + skip_vec[species[n] * 64 + lane];
    float v0 = a1x + c1x, v1 = a1y + c1y, v2 = a1z + c1z;
    float t0 = a2a + c2a, t1 = a2b + c2b, t2 = a2c + c2c, t3 = a2d + c2d, t4 = a2e + c2e;

    ss[wave][lane] = s;
    float g1a = 0.0f, g2a = 0.0f;
    #pragma unroll 4
    for (int c = 0; c < 64; c++) {
        float sc = ss[wave][c];
        g1a += sc * gate_w[c * 128 + lane];
        g2a += sc * gate_w[c * 128 + 64 + lane];
    }
    float g1 = sigm_f(g1a), g2 = sigm_f(g2a);
    float s_out = s * sigm_f(s);
    float vo0 = v0 * g1, vo1 = v1 * g1, vo2 = v2 * g1;
    float to0 = t0 * g2, to1 = t1 * g2, to2 = t2 * g2, to3 = t3 * g2, to4 = t4 * g2;

    float pfo = s_out * focus_w[lane]
              + vo0 * focus_w[64 + lane * 3 + 0]
              + vo1 * focus_w[64 + lane * 3 + 1]
              + vo2 * focus_w[64 + lane * 3 + 2]
              + to0 * focus_w[256 + lane * 5 + 0]
              + to1 * focus_w[256 + lane * 5 + 1]
              + to2 * focus_w[256 + lane * 5 + 2]
              + to3 * focus_w[256 + lane * 5 + 3]
              + to4 * focus_w[256 + lane * 5 + 4];
    #pragma unroll
    for (int off = 32; off > 0; off >>= 1) pfo += __shfl_down(pfo, off);
    if (lane == 0) out_focus[n] = pfo + focus_b[0];

    int fg = flags[n];
    if (fg) {
        float* fe = focus_emb + (size_t)(fg - 1) * FLATDIM;
        fe[lane] = s_out;
        fe[64 + lane * 3 + 0] = vo0;
        fe[64 + lane * 3 + 1] = vo1;
        fe[64 + lane * 3 + 2] = vo2;
        fe[256 + lane * 5 + 0] = to0;
        fe[256 + lane * 5 + 1] = to1;
        fe[256 + lane * 5 + 2] = to2;
        fe[256 + lane * 5 + 3] = to3;
        fe[256 + lane * 5 + 4] = to4;

        #pragma unroll
        for (int j = 0; j < 5; j++) {
            float acc = s_out * species_w[lane * 5 + j]
                      + vo0 * species_w[(64 + lane * 3 + 0) * 5 + j]
                      + vo1 * species_w[(64 + lane * 3 + 1) * 5 + j]
                      + vo2 * species_w[(64 + lane * 3 + 2) * 5 + j]
                      + to0 * species_w[(256 + lane * 5 + 0) * 5 + j]
                      + to1 * species_w[(256 + lane * 5 + 1) * 5 + j]
                      + to2 * species_w[(256 + lane * 5 + 2) * 5 + j]
                      + to3 * species_w[(256 + lane * 5 + 3) * 5 + j]
                      + to4 * species_w[(256 + lane * 5 + 4) * 5 + j];
            #pragma unroll
            for (int off = 32; off > 0; off >>= 1) acc += __shfl_down(acc, off);
            if (lane == 0) out_species[(fg - 1) * 5 + j] = acc + species_b[j];
        }
    }
}

// ---- pos head: grid = 100 graphs x 16 k-splits; plain stores to partial buffer ----
__global__ __launch_bounds__(256) void pos_kernel(
    const float* __restrict__ focus_emb, const int* __restrict__ target_species,
    const float* __restrict__ species_embed,
    const unsigned* __restrict__ posw_bf,
    float* __restrict__ partial)
{
    int g  = blockIdx.x >> 4;
    int ks = blockIdx.x & 15;
    int k0 = ks * 40;
    int tid = threadIdx.x;
    __shared__ float pin[40];

    if (tid < 40) {
        int k = k0 + tid;
        pin[tid] = (k < FLATDIM) ? focus_emb[(size_t)g * FLATDIM + k]
                                 : species_embed[target_species[g] * CC + (k - FLATDIM)];
    }
    __syncthreads();

    if (tid < 200) {
        float a0 = 0, a1 = 0, a2 = 0, a3 = 0, a4 = 0, a5 = 0, a6 = 0, a7 = 0;
        const unsigned* wp = posw_bf + (size_t)k0 * 800 + tid * 4;
        #pragma unroll 4
        for (int kk = 0; kk < 40; kk++) {
            uint4 wv = *reinterpret_cast<const uint4*>(wp + (size_t)kk * 800);
            float p = pin[kk];
            a0 += p * bf_lo(wv.x); a1 += p * bf_hi(wv.x);
            a2 += p * bf_lo(wv.y); a3 += p * bf_hi(wv.y);
            a4 += p * bf_lo(wv.z); a5 += p * bf_hi(wv.z);
            a6 += p * bf_lo(wv.w); a7 += p * bf_hi(wv.w);
        }
        float* op = partial + ((size_t)(g * 16 + ks)) * POSOUT + tid * 8;
        *reinterpret_cast<float4*>(op)     = make_float4(a0, a1, a2, a3);
        *reinterpret_cast<float4*>(op + 4) = make_float4(a4, a5, a6, a7);
    }
}

// ---- pos reduce: out_pos[g][o] = pos_b[o] + sum_ks partial[g][ks][o] ----
__global__ __launch_bounds__(256) void posred_kernel(
    const float* __restrict__ partial, const float* __restrict__ pos_b,
    float* __restrict__ out_pos)
{
    int g    = blockIdx.x >> 1;
    int half = blockIdx.x & 1;
    const float* pg = partial + (size_t)g * 16 * POSOUT;
    for (int o = half * 800 + threadIdx.x; o < half * 800 + 800; o += 256) {
        float a = pos_b[o];
        #pragma unroll
        for (int ks = 0; ks < 16; ks++) a += pg[ks * POSOUT + o];
        out_pos[(size_t)g * POSOUT + o] = a;
    }
}

extern "C" void kernel_launch(void* const* d_in, const int* in_sizes, int n_in,
                              void* d_out, int out_size, void* d_ws, size_t ws_size,
                              hipStream_t stream) {
    const float* positions      = (const float*)d_in[0];
    const int*   species        = (const int*)  d_in[1];
    const int*   senders        = (const int*)  d_in[2];
    const int*   receivers      = (const int*)  d_in[3];
    const int*   n_node         = (const int*)  d_in[4];
    const int*   target_species = (const int*)  d_in[5];
    const float* species_embed  = (const float*)d_in[6];
    const float* node_embed     = (const float*)d_in[7];
    const float* radial_w1      = (const float*)d_in[8];
    const float* radial_w2      = (const float*)d_in[9];
    const float* radial_w3      = (const float*)d_in[10];
    const float* lin_w0         = (const float*)d_in[11];
    const float* lin_w1         = (const float*)d_in[12];
    const float* lin_w2         = (const float*)d_in[13];
    const float* skip_w         = (const float*)d_in[14];
    const float* gate_w         = (const float*)d_in[15];
    const float* focus_w        = (const float*)d_in[16];
    const float* focus_b        = (const float*)d_in[17];
    const float* species_w      = (const float*)d_in[18];
    const float* species_b      = (const float*)d_in[19];
    const float* pos_w          = (const float*)d_in[20];
    const float* pos_b          = (const float*)d_in[21];

    // ws layout:
    //   payload [(320000+4 trash)*100 u32]   (pos partial[100*16*1600 f32] ALIASES
    //       the payload head: payload is dead after node_kernel each launch)
    // | posw_bf [512000 u32]
    // | eperm [320320 int]
    // | degree[20000] cursor[20000] flags[20000] (zeroed together)
    // | spcnt[5] grant[5] pad[6] (zeroed with above)
    // | start[20001] pstart[6]
    // | w1tn_g[256 u32] w2tn_g[2048 u32] w3l_g[30720 u32]
    // | skip_vec[320 f32] | focus_emb[57600 f32]
    unsigned* payload = (unsigned*)d_ws;
    float*    partial = (float*)d_ws;     // alias, used after node_kernel
    unsigned* posw_bf = payload + (size_t)(NEDGES + 4) * (PAYL / 2);
    int* eperm  = (int*)(posw_bf + 640 * 800);
    int* degree = eperm + EPERM_N;
    int* cursor = degree + NNODES;
    int* flags  = cursor + NNODES;
    int* spcnt  = flags + NNODES;
    int* grant  = spcnt + 5;
    int* start  = grant + 5 + 6;
    int* pstart = start + NNODES + 1;
    unsigned* w1tn_g = (unsigned*)(pstart + 6);
    unsigned* w2tn_g = w1tn_g + 256;
    unsigned* w3l_g  = w2tn_g + 2048;
    float* skip_vec  = (float*)(w3l_g + 15 * 2048);
    float* focus_emb = skip_vec + 320;

    float* out       = (float*)d_out;
    float* out_focus = out;
    float* out_spec  = out + NNODES;
    float* out_pos   = out + NNODES + NGRAPHS * 5;

    hipMemsetAsync(eperm, 0xFF, EPERM_N * sizeof(int), stream);
    hipMemsetAsync(degree, 0, (3 * NNODES + 16) * sizeof(int), stream);

    prep_kernel<<<512, 256, 0, stream>>>(radial_w1, radial_w2, radial_w3,
                                         lin_w0, lin_w1, lin_w2,
                                         skip_w, node_embed, pos_w,
                                         senders, receivers, species,
                                         w1tn_g, w2tn_g, w3l_g, skip_vec, posw_bf,
                                         degree, spcnt);
    scan_kernel<<<1, 1024, 0, stream>>>(degree, spcnt, n_node, start, pstart, flags);
    bucket_kernel<<<NEDGES / 256, 256, 0, stream>>>(senders, species, pstart, grant, eperm);

    edge_kernel<<<EPERM_N / 64, 256, 0, stream>>>(
        positions, species, senders, receivers,
        w1tn_g, w2tn_g, w3l_g, start, cursor, eperm, pstart, payload);

    node_kernel<<<NNODES / 4, 256, 0, stream>>>(
        payload, start, species, skip_vec,
        gate_w, focus_w, focus_b, flags,
        species_w, species_b, out_focus, out_spec, focus_emb);

    // payload is dead from here on; its head is reused as the pos partial buffer
    pos_kernel<<<NGRAPHS * 16, 256, 0, stream>>>(
        focus_emb, target_species, species_embed, posw_bf, partial);

    posred_kernel<<<NGRAPHS * 2, 256, 0, stream>>>(partial, pos_b, out_pos);
}